// Round 1
// baseline (669.771 us; speedup 1.0000x reference)
//
#include <hip/hip_runtime.h>
#include <hip/hip_bf16.h>
#include <stdint.h>

// ---------------------------------------------------------------------------
// Int8Linear: y = x @ Wq^T + b, Wq = dequant(int8-quant(W)) per-tensor absmax.
// Strategy: quantize W -> bf16 workspace, cast x -> bf16 workspace, then
// m97-style bf16 MFMA GEMM (16x16x32, 128x128 tile, global_load_lds width=16).
// Workspace layout: [0..4) absmax bits | 256 + x_bf16 (64 MiB) | wq_bf16 (32 MiB)
// ---------------------------------------------------------------------------

typedef __attribute__((ext_vector_type(8))) short short8;   // 8 x bf16 (4 VGPRs)
typedef __attribute__((ext_vector_type(4))) float f32x4;    // MFMA accumulator

#define BM 128
#define BN 128
#define BK 32

// float -> bf16, round-to-nearest-even (matches __float2bfloat16, no NaN here)
__device__ __forceinline__ unsigned short f2bf(float f) {
    unsigned u = __float_as_uint(f);
    unsigned r = 0x7fffu + ((u >> 16) & 1u);
    return (unsigned short)((u + r) >> 16);
}

// ---------------- absmax over W (n4 = n/4 float4s) -------------------------
__global__ void absmax_kernel(const float* __restrict__ W,
                              unsigned* __restrict__ out, int n4) {
    int i = blockIdx.x * blockDim.x + threadIdx.x;
    int stride = gridDim.x * blockDim.x;
    float m = 0.f;
    for (int idx = i; idx < n4; idx += stride) {
        float4 v = ((const float4*)W)[idx];
        m = fmaxf(m, fmaxf(fmaxf(fabsf(v.x), fabsf(v.y)),
                           fmaxf(fabsf(v.z), fabsf(v.w))));
    }
    #pragma unroll
    for (int off = 32; off > 0; off >>= 1)
        m = fmaxf(m, __shfl_down(m, off));
    if ((threadIdx.x & 63) == 0)
        atomicMax(out, __float_as_uint(m));   // |w| >= 0: uint bits monotone
}

// ---------------- quantize W -> bf16 ---------------------------------------
__global__ void quantize_kernel(const float* __restrict__ W,
                                const unsigned* __restrict__ amax,
                                unsigned short* __restrict__ Wq, int n4) {
    const float scale = __uint_as_float(*amax) / 127.0f;
    int i = blockIdx.x * blockDim.x + threadIdx.x;
    int stride = gridDim.x * blockDim.x;
    for (int idx = i; idx < n4; idx += stride) {
        float4 w = ((const float4*)W)[idx];
        float q0 = fminf(fmaxf(rintf(w.x / scale), -127.f), 127.f) * scale;
        float q1 = fminf(fmaxf(rintf(w.y / scale), -127.f), 127.f) * scale;
        float q2 = fminf(fmaxf(rintf(w.z / scale), -127.f), 127.f) * scale;
        float q3 = fminf(fmaxf(rintf(w.w / scale), -127.f), 127.f) * scale;
        ushort4 o;
        o.x = f2bf(q0); o.y = f2bf(q1); o.z = f2bf(q2); o.w = f2bf(q3);
        ((ushort4*)Wq)[idx] = o;
    }
}

// ---------------- cast x -> bf16 -------------------------------------------
__global__ void cast_kernel(const float* __restrict__ X,
                            unsigned short* __restrict__ Xb, int n4) {
    int i = blockIdx.x * blockDim.x + threadIdx.x;
    int stride = gridDim.x * blockDim.x;
    for (int idx = i; idx < n4; idx += stride) {
        float4 v = ((const float4*)X)[idx];
        ushort4 o;
        o.x = f2bf(v.x); o.y = f2bf(v.y); o.z = f2bf(v.z); o.w = f2bf(v.w);
        ((ushort4*)Xb)[idx] = o;
    }
}

// ---------------- bf16 NT GEMM: C[M,N] = A[M,K] * B[N,K]^T + bias ----------
// Block = 256 threads = 4 waves (2x2), each wave does a 64x64 tile as 4x4
// mfma_f32_16x16x32_bf16. Staging via global_load_lds width=16:
// LDS layout is exactly wave-contiguous (base + lane*16B) -- no padding.
typedef __attribute__((address_space(3))) void lds_void;
typedef __attribute__((address_space(1))) void gbl_void;

__global__ __launch_bounds__(256) void gemm_bt(
    const unsigned short* __restrict__ A,   // [M,K] bf16 bits
    const unsigned short* __restrict__ B,   // [N,K] bf16 bits
    const float* __restrict__ bias,         // [N]
    float* __restrict__ C, int M, int N, int K)
{
    __shared__ __align__(16) unsigned short sA[BM * BK];  // 8 KiB
    __shared__ __align__(16) unsigned short sB[BN * BK];  // 8 KiB

    const int tid  = threadIdx.x;
    const int wave = tid >> 6;
    const int lane = tid & 63;

    const int rowBase = blockIdx.y * BM;   // M tile
    const int colBase = blockIdx.x * BN;   // N tile

    const int wr = wave >> 1;              // 0..1 : wave row in 2x2
    const int wc = wave & 1;               // 0..1 : wave col

    f32x4 acc[4][4];
    #pragma unroll
    for (int i = 0; i < 4; ++i)
        #pragma unroll
        for (int j = 0; j < 4; ++j)
            acc[i][j] = (f32x4){0.f, 0.f, 0.f, 0.f};

    // staging: per issue, a wave covers 16 rows x 32 cols (64 B/row)
    const int lrow = lane >> 2;            // 0..15
    const int lcol = (lane & 3) * 8;       // 0,8,16,24 (elements)

    const int fr = lane & 15;              // fragment row/col index
    const int fq = (lane >> 4) * 8;        // k offset within BK

    const int kIters = K / BK;
    for (int kk = 0; kk < kIters; ++kk) {
        const int k0 = kk * BK;
        #pragma unroll
        for (int j = 0; j < 2; ++j) {
            const int g = j * 4 + wave;    // 16-row group 0..7
            const unsigned short* ga =
                A + (size_t)(rowBase + g * 16 + lrow) * K + (k0 + lcol);
            __builtin_amdgcn_global_load_lds((gbl_void*)ga,
                (lds_void*)&sA[g * 16 * BK], 16, 0, 0);
        }
        #pragma unroll
        for (int j = 0; j < 2; ++j) {
            const int g = j * 4 + wave;
            const unsigned short* gb =
                B + (size_t)(colBase + g * 16 + lrow) * K + (k0 + lcol);
            __builtin_amdgcn_global_load_lds((gbl_void*)gb,
                (lds_void*)&sB[g * 16 * BK], 16, 0, 0);
        }
        __syncthreads();   // drains vmcnt (global_load_lds) + lgkmcnt

        short8 afrag[4], bfrag[4];
        #pragma unroll
        for (int mt = 0; mt < 4; ++mt)
            afrag[mt] = *(const short8*)&sA[(wr * 64 + mt * 16 + fr) * BK + fq];
        #pragma unroll
        for (int nt = 0; nt < 4; ++nt)
            bfrag[nt] = *(const short8*)&sB[(wc * 64 + nt * 16 + fr) * BK + fq];

        #pragma unroll
        for (int mt = 0; mt < 4; ++mt)
            #pragma unroll
            for (int nt = 0; nt < 4; ++nt)
                acc[mt][nt] = __builtin_amdgcn_mfma_f32_16x16x32_bf16(
                    afrag[mt], bfrag[nt], acc[mt][nt], 0, 0, 0);

        __syncthreads();   // protect LDS from next iteration's staging
    }

    // epilogue: C/D layout col=lane&15, row=(lane>>4)*4+reg
    const int quad = lane >> 4;
    #pragma unroll
    for (int nt = 0; nt < 4; ++nt) {
        const int col = colBase + wc * 64 + nt * 16 + fr;
        const float bv = bias[col];
        #pragma unroll
        for (int mt = 0; mt < 4; ++mt) {
            const int row0 = rowBase + wr * 64 + mt * 16 + quad * 4;
            #pragma unroll
            for (int r = 0; r < 4; ++r)
                C[(size_t)(row0 + r) * N + col] = acc[mt][nt][r] + bv;
        }
    }
}

// ---------------------------------------------------------------------------
extern "C" void kernel_launch(void* const* d_in, const int* in_sizes, int n_in,
                              void* d_out, int out_size, void* d_ws, size_t ws_size,
                              hipStream_t stream) {
    const float* x = (const float*)d_in[0];   // [M,K]
    const float* W = (const float*)d_in[1];   // [N,K]
    const float* b = (const float*)d_in[2];   // [N]
    float* out = (float*)d_out;               // [M,N]

    const int N = in_sizes[2];                // 4096
    const int K = in_sizes[1] / N;            // 4096
    const int M = in_sizes[0] / K;            // 8192

    unsigned char* ws = (unsigned char*)d_ws;
    unsigned* amax = (unsigned*)ws;
    unsigned short* xb = (unsigned short*)(ws + 256);
    unsigned short* wq = (unsigned short*)(ws + 256 + (size_t)M * K * 2);

    hipMemsetAsync(amax, 0, 4, stream);       // ws is re-poisoned every call

    absmax_kernel<<<1024, 256, 0, stream>>>(W, amax, (N * K) / 4);
    quantize_kernel<<<2048, 256, 0, stream>>>(W, amax, wq, (N * K) / 4);
    cast_kernel<<<4096, 256, 0, stream>>>(x, xb, (M * K) / 4);

    dim3 grid(N / BN, M / BM);                // (32, 64)
    gemm_bt<<<grid, 256, 0, stream>>>(xb, wq, b, out, M, N, K);
}